// Round 6
// baseline (123.577 us; speedup 1.0000x reference)
//
#include <hip/hip_runtime.h>
#include <math.h>

#define PI_F 3.14159265358979323846f
#define KSTEP 0.21959209425992272f /* (log2(224)-1)/31 */

using bf16x8 = __attribute__((ext_vector_type(8))) short;
using f32x4 = __attribute__((ext_vector_type(4))) float;
using u16x8 = __attribute__((ext_vector_type(8))) unsigned short;

static __device__ __forceinline__ float wave_reduce_sum(float v) {
#pragma unroll
  for (int off = 32; off; off >>= 1) v += __shfl_down(v, off);
  return v;
}

static __device__ __forceinline__ unsigned short f2bf(float f) {
  unsigned u = __float_as_uint(f);
  return (unsigned short)((u + 0x7fffu + ((u >> 16) & 1u)) >> 16);
}

static __device__ __forceinline__ float bf2f(unsigned short s) {
  return __uint_as_float(((unsigned)s) << 16);
}

static __device__ __forceinline__ void gload_lds16(const void* g, void* l) {
  __builtin_amdgcn_global_load_lds((const __attribute__((address_space(1))) unsigned int*)g,
                                   (__attribute__((address_space(3))) unsigned int*)l, 16, 0, 0);
}

// ---------------- fused prep: transpose x->bf16 x_t + t_mean | Wk->bf16 | sc table ----------------
__global__ __launch_bounds__(256) void prep_kernel(const float* __restrict__ x,
                                                   const float* __restrict__ qkv_w,
                                                   unsigned short* __restrict__ xt,
                                                   float* __restrict__ t_mean,
                                                   unsigned short* __restrict__ wk_bf,
                                                   float2* __restrict__ sc) {
  const int bid = blockIdx.x;
  const int t = threadIdx.x;
  __shared__ float tile[64][33];
  if (bid < 1024) {
    const int ct = bid & 15, b = bid >> 4;
    const int cl = t >> 2, pq = (t & 3) * 8;  // read role
    const int pl = t >> 3, cq = (t & 7) * 8;  // write role
    float sum = 0.0f;
    const float* xrow = x + ((size_t)(b * 1024 + ct * 64 + cl) * 256) + pq;
    unsigned short* xtb = xt + (size_t)b * 262144 + ct * 64;
    for (int pt = 0; pt < 8; ++pt) {
      const float4 v0 = *reinterpret_cast<const float4*>(xrow + pt * 32);
      const float4 v1 = *reinterpret_cast<const float4*>(xrow + pt * 32 + 4);
      tile[cl][pq + 0] = v0.x; tile[cl][pq + 1] = v0.y; tile[cl][pq + 2] = v0.z; tile[cl][pq + 3] = v0.w;
      tile[cl][pq + 4] = v1.x; tile[cl][pq + 5] = v1.y; tile[cl][pq + 6] = v1.z; tile[cl][pq + 7] = v1.w;
      sum += (v0.x + v0.y) + (v0.z + v0.w) + (v1.x + v1.y) + (v1.z + v1.w);
      __syncthreads();
      u16x8 o;
#pragma unroll
      for (int e = 0; e < 8; ++e) o[e] = f2bf(tile[cq + e][pl]);
      *reinterpret_cast<u16x8*>(xtb + (size_t)(pt * 32 + pl) * 1024 + cq) = o;
      __syncthreads();
    }
    sum += __shfl_xor(sum, 1);
    sum += __shfl_xor(sum, 2);
    if ((t & 3) == 0) t_mean[b * 1024 + ct * 64 + cl] = sum * (1.0f / 256.0f);
  } else if (bid < 2048) {
    const int i = ((bid - 1024) * 256 + t) * 4;
    const float4 v = *reinterpret_cast<const float4*>(qkv_w + 1048576 + i);
    ushort4 r;
    r.x = f2bf(v.x); r.y = f2bf(v.y); r.z = f2bf(v.z); r.w = f2bf(v.w);
    *reinterpret_cast<ushort4*>(wk_bf + i) = r;
  } else {
    const int idx = (bid - 2048) * 256 + t;  // 16384
    const int m = idx >> 8, j = idx & 255;
    const float band = exp2f((float)(m & 31) * KSTEP) * PI_F;
    const float coord = (m < 32) ? (-1.0f + (2.0f / 15.0f) * (float)(j >> 4))
                                 : (-1.0f + (2.0f / 15.0f) * (float)(j & 15));
    float sn, cs;
    sincosf(coord * band, &sn, &cs);
    sc[idx] = make_float2(sn, cs);
  }
}

// ---------------- split-K skinny GEMM: Cp[kc] = A * B^T (K-chunk = 256) ----------------
__global__ __launch_bounds__(256) void gemm_splitk(
    const float* __restrict__ A, int lda, int aStrideZ,
    const float* __restrict__ B, int ldb, int bStrideZ,
    float* __restrict__ Cp, int ldc, int cStrideZ, int cStrideKc, int KC) {
  const int nt = blockIdx.x, mt = blockIdx.y;
  const int z = blockIdx.z / KC, kc = blockIdx.z % KC;
  const int tid = threadIdx.x;
  A += (size_t)z * aStrideZ + (size_t)mt * 32 * lda + kc * 256;
  B += (size_t)z * bStrideZ + (size_t)nt * 64 * ldb + kc * 256;
  Cp += (size_t)kc * cStrideKc + (size_t)z * cStrideZ + (size_t)mt * 32 * ldc + nt * 64;

  __shared__ float As[32][34];
  __shared__ float Bs[32][68];

  const int tm = tid >> 4;
  const int tn = tid & 15;
  float acc0[4] = {0, 0, 0, 0}, acc1[4] = {0, 0, 0, 0};

  for (int k0 = 0; k0 < 256; k0 += 32) {
    {
      const int m = tid >> 3, kq = tid & 7;
      float4 v = *reinterpret_cast<const float4*>(A + (size_t)m * lda + k0 + kq * 4);
      As[kq * 4 + 0][m] = v.x; As[kq * 4 + 1][m] = v.y;
      As[kq * 4 + 2][m] = v.z; As[kq * 4 + 3][m] = v.w;
    }
#pragma unroll
    for (int r = 0; r < 2; ++r) {
      const int idx = r * 256 + tid;
      const int n = idx >> 3, kq = idx & 7;
      float4 v = *reinterpret_cast<const float4*>(B + (size_t)n * ldb + k0 + kq * 4);
      Bs[kq * 4 + 0][n] = v.x; Bs[kq * 4 + 1][n] = v.y;
      Bs[kq * 4 + 2][n] = v.z; Bs[kq * 4 + 3][n] = v.w;
    }
    __syncthreads();
#pragma unroll
    for (int k = 0; k < 32; ++k) {
      const float a0 = As[k][tm * 2], a1 = As[k][tm * 2 + 1];
      const float4 bb = *reinterpret_cast<const float4*>(&Bs[k][tn * 4]);
      acc0[0] += a0 * bb.x; acc0[1] += a0 * bb.y; acc0[2] += a0 * bb.z; acc0[3] += a0 * bb.w;
      acc1[0] += a1 * bb.x; acc1[1] += a1 * bb.y; acc1[2] += a1 * bb.z; acc1[3] += a1 * bb.w;
    }
    __syncthreads();
  }
  *reinterpret_cast<float4*>(Cp + (size_t)(tm * 2) * ldc + tn * 4) =
      make_float4(acc0[0], acc0[1], acc0[2], acc0[3]);
  *reinterpret_cast<float4*>(Cp + (size_t)(tm * 2 + 1) * ldc + tn * 4) =
      make_float4(acc1[0], acc1[1], acc1[2], acc1[3]);
}

// ---------------- proj GEMM with inline 8-partial A reduce + Wv-bias ----------------
// A[m][k] = bias_v[k] + sum_{ct=0..7} out0_part[ct][m][k]; C partials by kc.
__global__ __launch_bounds__(256) void gemm_proj_splitk(
    const float* __restrict__ Apart, const float* __restrict__ abias,
    const float* __restrict__ B, float* __restrict__ Cp) {
  const int nt = blockIdx.x, mt = blockIdx.y, kc = blockIdx.z;
  const int tid = threadIdx.x;
  B += (size_t)nt * 64 * 1024 + kc * 256;
  Cp += (size_t)kc * 65536 + (size_t)mt * 32 * 1024 + nt * 64;

  __shared__ float As[32][34];
  __shared__ float Bs[32][68];

  const int tm = tid >> 4;
  const int tn = tid & 15;
  float acc0[4] = {0, 0, 0, 0}, acc1[4] = {0, 0, 0, 0};

  for (int k0 = 0; k0 < 256; k0 += 32) {
    {
      const int m = tid >> 3, kq = tid & 7;
      const int kg = kc * 256 + k0 + kq * 4;
      const float* Ab = Apart + (size_t)(mt * 32 + m) * 1024 + kg;
      float4 v = *reinterpret_cast<const float4*>(abias + kg);
#pragma unroll
      for (int r = 0; r < 8; ++r) {
        const float4 p = *reinterpret_cast<const float4*>(Ab + (size_t)r * 65536);
        v.x += p.x; v.y += p.y; v.z += p.z; v.w += p.w;
      }
      As[kq * 4 + 0][m] = v.x; As[kq * 4 + 1][m] = v.y;
      As[kq * 4 + 2][m] = v.z; As[kq * 4 + 3][m] = v.w;
    }
#pragma unroll
    for (int r = 0; r < 2; ++r) {
      const int idx = r * 256 + tid;
      const int n = idx >> 3, kq = idx & 7;
      float4 v = *reinterpret_cast<const float4*>(B + (size_t)n * 1024 + k0 + kq * 4);
      Bs[kq * 4 + 0][n] = v.x; Bs[kq * 4 + 1][n] = v.y;
      Bs[kq * 4 + 2][n] = v.z; Bs[kq * 4 + 3][n] = v.w;
    }
    __syncthreads();
#pragma unroll
    for (int k = 0; k < 32; ++k) {
      const float a0 = As[k][tm * 2], a1 = As[k][tm * 2 + 1];
      const float4 bb = *reinterpret_cast<const float4*>(&Bs[k][tn * 4]);
      acc0[0] += a0 * bb.x; acc0[1] += a0 * bb.y; acc0[2] += a0 * bb.z; acc0[3] += a0 * bb.w;
      acc1[0] += a1 * bb.x; acc1[1] += a1 * bb.y; acc1[2] += a1 * bb.z; acc1[3] += a1 * bb.w;
    }
    __syncthreads();
  }
  *reinterpret_cast<float4*>(Cp + (size_t)(tm * 2) * 1024 + tn * 4) =
      make_float4(acc0[0], acc0[1], acc0[2], acc0[3]);
  *reinterpret_cast<float4*>(Cp + (size_t)(tm * 2 + 1) * 1024 + tn * 4) =
      make_float4(acc1[0], acc1[1], acc1[2], acc1[3]);
}

// ---------------- reduce 4 split-K partials + bias ----------------
__global__ __launch_bounds__(256) void reduce4_bias(const float* __restrict__ part,
                                                    const float* __restrict__ bias,
                                                    float* __restrict__ out) {
  const int i = blockIdx.x * 256 + threadIdx.x;  // 65536
  out[i] = part[i] + part[i + 65536] + part[i + 131072] + part[i + 196608] + bias[i & 1023];
}

// ---------------- MFMA K-GEMM + RoPE-dot + fused softmax ----------------
// Block (b,h): K_h[128 d][256 j], K=1024, BK=32, 3 LDS buffers (72 KB ->
// 2 blocks/CU), counted vmcnt(6) 2-deep prefetch. Epilogue: q0/k0 reduce,
// RoPE-rotated dot, full per-head softmax -> attn.
__global__ __launch_bounds__(512, 4) void k_scores_mfma(
    const unsigned short* __restrict__ wk, const unsigned short* __restrict__ xt,
    const float* __restrict__ qkv_b, const float* __restrict__ q0p,
    const float2* __restrict__ sc, float* __restrict__ attn) {
  const int l = blockIdx.x;  // 512; same-b blocks share an XCD (l&7 preserved)
  const int b = ((l >> 6) << 3) | (l & 7);
  const int h = (l >> 3) & 7;
  const int tid = threadIdx.x;
  const int w = tid >> 6, lane = tid & 63;
  const int wr = w >> 2, wc = w & 3;  // wave tile: 64d x 64j

  __shared__ __align__(16) char smem[73728];  // 3 bufs x (A 8KB + B 16KB)

  const unsigned short* wkh = wk + (size_t)h * 131072;
  const unsigned short* xtb = xt + (size_t)b * 262144;

  f32x4 acc[4][4] = {};

  // Stage one BK=32 tile; 3 gloads/wave (1 A + 2 B). Source c-chunk
  // pre-swizzled so linear LDS dest + swizzled ds_read match (rule 21).
#define STAGE6(buf, c0)                                                     \
  {                                                                         \
    char* Ab_ = smem + (buf)*24576;                                         \
    char* Bb_ = Ab_ + 8192;                                                 \
    {                                                                       \
      const int row_ = w * 16 + (lane >> 2);                                \
      const int sl_ = ((lane & 3) ^ ((row_ >> 1) & 3)) * 8;                 \
      gload_lds16(wkh + (size_t)row_ * 1024 + (c0) + sl_, Ab_ + w * 1024);  \
    }                                                                       \
    _Pragma("unroll") for (int i = 0; i < 2; ++i) {                         \
      const int row_ = w * 32 + i * 16 + (lane >> 2);                       \
      const int sl_ = ((lane & 3) ^ ((row_ >> 1) & 3)) * 8;                 \
      gload_lds16(xtb + (size_t)row_ * 1024 + (c0) + sl_,                   \
                  Bb_ + (w * 2 + i) * 1024);                                \
    }                                                                       \
  }

  STAGE6(0, 0);
  STAGE6(1, 32);
  int cur = 0, nxt = 2;
  for (int t = 0; t < 32; ++t) {
    {  // stage tile t+2 (clamped at tail; stray writes land in consumed bufs)
      const int src = (t + 2 > 31) ? 31 : (t + 2);
      STAGE6(nxt, src * 32);
    }
    asm volatile("s_waitcnt vmcnt(6)" ::: "memory");  // tile t resident; 2 tiles in flight
    __builtin_amdgcn_s_barrier();
    const char* Ab = smem + cur * 24576;
    const char* Bb = Ab + 8192;
    bf16x8 af[4], bfr[4];
#pragma unroll
    for (int mi = 0; mi < 4; ++mi) {
      const int row = wr * 64 + mi * 16 + (lane & 15);
      af[mi] = *reinterpret_cast<const bf16x8*>(
          Ab + row * 64 + (((lane >> 4) ^ ((row >> 1) & 3)) << 4));
    }
#pragma unroll
    for (int ni = 0; ni < 4; ++ni) {
      const int row = wc * 64 + ni * 16 + (lane & 15);
      bfr[ni] = *reinterpret_cast<const bf16x8*>(
          Bb + row * 64 + (((lane >> 4) ^ ((row >> 1) & 3)) << 4));
    }
    __builtin_amdgcn_s_setprio(1);
#pragma unroll
    for (int mi = 0; mi < 4; ++mi)
#pragma unroll
      for (int ni = 0; ni < 4; ++ni)
        acc[mi][ni] =
            __builtin_amdgcn_mfma_f32_16x16x32_bf16(af[mi], bfr[ni], acc[mi][ni], 0, 0, 0);
    __builtin_amdgcn_s_setprio(0);
    __builtin_amdgcn_s_barrier();  // readers done before buf[nxt-ish] overwrite
    asm volatile("" ::: "memory");
    cur = (cur == 2) ? 0 : cur + 1;
    nxt = (nxt == 2) ? 0 : nxt + 1;
  }
#undef STAGE6

  asm volatile("s_waitcnt vmcnt(0)" ::: "memory");  // drain strays before LDS reuse
  __syncthreads();

  // LDS reuse for epilogue
  float* q0_lds = reinterpret_cast<float*>(smem);  // [128]
  float* k0_lds = q0_lds + 128;                    // [128]
  float* red2 = k0_lds + 128;                      // [256 j][2 wr]
  float* ps = red2 + 512;                          // [2] token-0 partials
  float* r4a = ps + 2;                             // [4] softmax max
  float* r4b = r4a + 4;                            // [4] softmax sum

  if (tid < 128) {
    const float* qp = q0p + (size_t)b * 2048 + h * 128 + tid;
    q0_lds[tid] = qkv_b[h * 128 + tid] + qp[0] + qp[131072] + qp[262144] + qp[393216];
    const float* kp = qp + 1024;
    k0_lds[tid] = qkv_b[1024 + h * 128 + tid] + kp[0] + kp[131072] + kp[262144] + kp[393216];
  }
  __syncthreads();

  // token-0 score partials (waves 0-1 cover the 128 dims)
  if (tid < 128) {
    float pr = q0_lds[tid] * k0_lds[tid];
    pr = wave_reduce_sum(pr);
    if (lane == 0) ps[w] = pr;
  }

  // RoPE-rotated dot over this lane's acc rows
  const int colj = lane & 15, rgrp = lane >> 4;
  const float* bk = qkv_b + 1024 + h * 128;
  float partial[4] = {0, 0, 0, 0};
#pragma unroll
  for (int mi = 0; mi < 4; ++mi) {
#pragma unroll
    for (int pp = 0; pp < 2; ++pp) {
      const int dd = wr * 64 + mi * 16 + rgrp * 4 + pp * 2;  // dim within head
      const int m = dd >> 1;
      const float2 qv = *reinterpret_cast<const float2*>(q0_lds + dd);
      const float2 bv = *reinterpret_cast<const float2*>(bk + dd);
#pragma unroll
      for (int ni = 0; ni < 4; ++ni) {
        const int j = wc * 64 + ni * 16 + colj;
        const float ke = acc[mi][ni][pp * 2] + bv.x;
        const float ko = acc[mi][ni][pp * 2 + 1] + bv.y;
        const float2 tt = sc[m * 256 + j];
        partial[ni] += tt.y * (ke * qv.x + ko * qv.y) + tt.x * (ke * qv.y - ko * qv.x);
      }
    }
  }
#pragma unroll
  for (int ni = 0; ni < 4; ++ni) {
    partial[ni] += __shfl_xor(partial[ni], 16);
    partial[ni] += __shfl_xor(partial[ni], 32);
  }
  if (lane < 16) {
#pragma unroll
    for (int ni = 0; ni < 4; ++ni) red2[(wc * 64 + ni * 16 + colj) * 2 + wr] = partial[ni];
  }
  __syncthreads();  // red2 + ps ready

  // fused softmax over 257 tokens (threads 0..255; thread 0 also token 256)
  const float scale = 0.08838834764831845f;
  float va = -3.0e38f, vb = -3.0e38f;
  if (tid < 256) {
    va = scale * ((tid == 0) ? (ps[0] + ps[1]) : (red2[(tid - 1) * 2] + red2[(tid - 1) * 2 + 1]));
    if (tid == 0) vb = scale * (red2[255 * 2] + red2[255 * 2 + 1]);
  }
  float mx = fmaxf(va, vb);
  if (tid < 256) {
#pragma unroll
    for (int off = 32; off; off >>= 1) mx = fmaxf(mx, __shfl_xor(mx, off));
    if (lane == 0) r4a[w] = mx;
  }
  __syncthreads();
  const float gmx = fmaxf(fmaxf(r4a[0], r4a[1]), fmaxf(r4a[2], r4a[3]));
  float ea = 0.0f, eb = 0.0f;
  if (tid < 256) {
    ea = expf(va - gmx);
    eb = (tid == 0) ? expf(vb - gmx) : 0.0f;
    float sm = ea + eb;
#pragma unroll
    for (int off = 32; off; off >>= 1) sm += __shfl_xor(sm, off);
    if (lane == 0) r4b[w] = sm;
  }
  __syncthreads();
  if (tid < 256) {
    const float inv = 1.0f / (r4b[0] + r4b[1] + r4b[2] + r4b[3]);
    float* ab = attn + (size_t)(b * 8 + h) * 257;
    ab[tid] = ea * inv;
    if (tid == 0) ab[256] = eb * inv;
  }
}

// ---------------- fused u + out0 partials ----------------
// Phase 1: u_tile[8h][128c] = sum_j attn[b,h,j] * t_j[c-tile] (bf16 x_t).
// Phase 2: out0_part[ct][b][h*128+r] = Wv[h*128+r, c-tile] . u_tile[h].
__global__ __launch_bounds__(256) void u_out0_kernel(const unsigned short* __restrict__ xt,
                                                     const float* __restrict__ t_mean,
                                                     const float* __restrict__ attn,
                                                     const float* __restrict__ qkv_w,
                                                     float* __restrict__ out0_part) {
  const int ct = blockIdx.x;  // 8 tiles of 128 channels; ct -> XCD (Wv slice L2-local)
  const int b = blockIdx.y;   // 64
  const int tid = threadIdx.x;
  __shared__ float aw[2056];
  __shared__ float red[8192];  // [8 q][1024]
  __shared__ __align__(16) float u_lds[1024];  // [8 h][128 c]
  for (int i = tid; i < 2056; i += 256) aw[i] = attn[(size_t)(b * 8 + (i & 7)) * 257 + (i >> 3)];
  __syncthreads();
  const int cl = tid & 31, q = tid >> 5;
  const int c = ct * 128 + cl * 4;
  const unsigned short* xr = xt + (size_t)b * 262144 + c;
  float acc[8][4] = {};
  for (int p = q * 32; p < q * 32 + 32; ++p) {
    const ushort4 v = *reinterpret_cast<const ushort4*>(xr + (size_t)p * 1024);
    const float xs[4] = {bf2f(v.x), bf2f(v.y), bf2f(v.z), bf2f(v.w)};
    const float* w8 = &aw[(p + 1) * 8];
#pragma unroll
    for (int hh = 0; hh < 8; ++hh)
#pragma unroll
      for (int e = 0; e < 4; ++e) acc[hh][e] += w8[hh] * xs[e];
  }
#pragma unroll
  for (int hh = 0; hh < 8; ++hh)
#pragma unroll
    for (int e = 0; e < 4; ++e) red[q * 1024 + (cl * 8 + hh) * 4 + e] = acc[hh][e];
  __syncthreads();
#pragma unroll
  for (int r = 0; r < 4; ++r) {
    const int o = tid * 4 + r;  // 0..1023
    const int cl2 = o >> 5, hh = (o >> 2) & 7, e = o & 3;
    float s = 0.0f;
#pragma unroll
    for (int qq = 0; qq < 8; ++qq) s += red[qq * 1024 + o];
    s += aw[hh] * t_mean[b * 1024 + ct * 128 + cl2 * 4 + e];
    u_lds[hh * 128 + cl2 * 4 + e] = s;
  }
  __syncthreads();

  // Phase 2: 8 threads per output row; 32 rows per pass.
  const int lane7 = tid & 7;
  float* op = out0_part + (size_t)ct * 65536 + (size_t)b * 1024;
  for (int s = 0; s < 32; ++s) {
    const int o = (tid >> 3) + 32 * s;  // output dim h*128+r
    const float* wrow = qkv_w + (size_t)(2048 + o) * 1024 + ct * 128 + lane7 * 16;
    const float* ur = u_lds + (o >> 7) * 128 + lane7 * 16;
    float a = 0.0f;
#pragma unroll
    for (int i = 0; i < 4; ++i) {
      const float4 wv = *reinterpret_cast<const float4*>(wrow + i * 4);
      const float4 uv = *reinterpret_cast<const float4*>(ur + i * 4);
      a += wv.x * uv.x + wv.y * uv.y + wv.z * uv.z + wv.w * uv.w;
    }
    a += __shfl_xor(a, 1);
    a += __shfl_xor(a, 2);
    a += __shfl_xor(a, 4);
    if (lane7 == 0) op[o] = a;
  }
}

// ---------------- host side ----------------
extern "C" void kernel_launch(void* const* d_in, const int* in_sizes, int n_in,
                              void* d_out, int out_size, void* d_ws, size_t ws_size,
                              hipStream_t stream) {
  const float* x = (const float*)d_in[0];
  const float* qkv_w = (const float*)d_in[1];
  const float* qkv_b = (const float*)d_in[2];
  const float* proj_w = (const float*)d_in[3];
  const float* proj_b = (const float*)d_in[4];
  float* out = (float*)d_out;

  float* ws = (float*)d_ws;
  float* t_mean = ws;                                       // 65536
  float* q0k0_part = ws + 65536;                            // 524288
  float* attn = ws + 589824;                                // 131584
  float* out0_part = ws + 721408;                           // 8*64*1024 = 524288
  float* out_part = ws + 1245696;                           // 262144
  float2* sc = (float2*)(ws + 1507840);                     // 16384 float2
  unsigned short* wk_bf = (unsigned short*)(ws + 1540608);  // 1M u16
  unsigned short* x_t = (unsigned short*)(ws + 2064896);    // 16.78M u16

  // 1. fused prep: transpose+mean | wk->bf16 | sc table
  prep_kernel<<<2112, 256, 0, stream>>>(x, qkv_w, x_t, t_mean, wk_bf, sc);

  // 2. q0k0 partials: t_mean @ qkv_w[0:2048].T  (M=64,N=2048,K=4x256)
  gemm_splitk<<<dim3(32, 2, 4), 256, 0, stream>>>(t_mean, 1024, 0, qkv_w, 1024, 0,
                                                  q0k0_part, 2048, 0, 131072, 4);

  // 3. fused K-GEMM + RoPE + scores + softmax -> attn  (512 blocks = (b,h))
  k_scores_mfma<<<512, 512, 0, stream>>>(wk_bf, x_t, qkv_b, q0k0_part, sc, attn);

  // 4. fused u = attn^T * t and out0 c-chunk partials
  u_out0_kernel<<<dim3(8, 64), 256, 0, stream>>>(x_t, t_mean, attn, qkv_w, out0_part);

  // 5. proj partials, A = reduce8(out0_part)+bias_v inline
  gemm_proj_splitk<<<dim3(16, 2, 4), 256, 0, stream>>>(out0_part, qkv_b + 2048, proj_w, out_part);

  // 6. final reduce + proj bias
  reduce4_bias<<<256, 256, 0, stream>>>(out_part, proj_b, out);
}